// Round 1
// baseline (2132.224 us; speedup 1.0000x reference)
//
#include <hip/hip_runtime.h>

// Correlation (FlowNetC/PWC) cost volume, fused corr + 3x3 window sum.
// B=4 C=128 H=W=192, MAX_DISP=20 stride2=2 -> 21x21 displacements, K=3, PAD=3.
// out[b, dyi*21+dxi, i, j] = (1/1152) * sum_{c,wy,wx}
//     in1[b,c, i+wy+17, j+wx+17] * in2pad[b,c, i+wy+17+dy, j+wx+17+dx]
// with dy = 2*dyi-20, dx = 2*dxi-20, out spatial 156x156, corr grid 158x158.

#define C_    128
#define H_    192
#define W_    192
#define HW_   (H_ * W_)
#define OUT_HW 156
#define NDISP 21          // displacements per axis
#define TILE_OUT 14       // output tile edge
#define TILE_CORR 16      // corr tile edge = TILE_OUT + 2
#define S2W 56            // staged in2 width = TILE_CORR + 40
#define NT 256

__global__ __launch_bounds__(NT, 4)
void corr_kernel(const float* __restrict__ in1, const float* __restrict__ in2,
                 float* __restrict__ out) {
    __shared__ float s2s[TILE_CORR * S2W];                 // 896 floats
    __shared__ float corrs[NDISP * TILE_CORR * TILE_CORR]; // 5376 floats

    const int tid = threadIdx.x;
    const int tx = tid & 15;        // corr col within tile
    const int ty = tid >> 4;        // corr row within tile
    const int tj = blockIdx.x;
    const int ti = blockIdx.y;
    const int z  = blockIdx.z;      // b*21 + dyi
    const int b   = z / NDISP;
    const int dyi = z - b * NDISP;
    const int dy  = 2 * dyi - 20;

    const int y0 = ti * TILE_OUT;   // corr-tile origin
    const int x0 = tj * TILE_OUT;

    const int y = y0 + ty;          // this thread's corr row (may exceed 157: unused then)
    const int x = x0 + tx;          // this thread's corr col

    float acc[NDISP];
#pragma unroll
    for (int d = 0; d < NDISP; ++d) acc[d] = 0.f;

    // in1 read: rows y+17 <= 169+17 = 186 < 192, always in-bounds
    const float* p1 = in1 + (size_t)b * C_ * HW_ + (size_t)(y + 17) * W_ + (x + 17);
    const float* p2base = in2 + (size_t)b * C_ * HW_;

    for (int c = 0; c < C_; ++c) {
        const float a = p1[(size_t)c * HW_];
        const float* p2 = p2base + (size_t)c * HW_;

        // cooperative stage of the in2 row-band: rows y0+17+dy .. +15, cols x0-3 .. x0+52
        for (int idx = tid; idx < TILE_CORR * S2W; idx += NT) {
            const int r  = idx / S2W;
            const int cc = idx - r * S2W;
            const int gr = y0 + r + 17 + dy;
            const int gc = x0 + cc - 3;
            float v = 0.f;
            if ((unsigned)gr < H_ && (unsigned)gc < W_)
                v = p2[gr * W_ + gc];
            s2s[idx] = v;
        }
        __syncthreads();

        const float* srow = &s2s[ty * S2W + tx];
#pragma unroll
        for (int d = 0; d < NDISP; ++d)
            acc[d] += a * srow[2 * d];
        __syncthreads();
    }

    // dump corr tile (all 21 dx planes) to LDS
#pragma unroll
    for (int d = 0; d < NDISP; ++d)
        corrs[d * (TILE_CORR * TILE_CORR) + tid] = acc[d];
    __syncthreads();

    // 3x3 window sum + scaled store
    const float scale = 1.f / 1152.f;
    for (int o = tid; o < NDISP * TILE_OUT * TILE_OUT; o += NT) {
        const int d   = o / (TILE_OUT * TILE_OUT);
        const int rem = o - d * (TILE_OUT * TILE_OUT);
        const int i   = rem / TILE_OUT;
        const int j   = rem - i * TILE_OUT;
        const float* cp = &corrs[d * (TILE_CORR * TILE_CORR) + i * TILE_CORR + j];
        const float s = cp[0]  + cp[1]  + cp[2]
                      + cp[16] + cp[17] + cp[18]
                      + cp[32] + cp[33] + cp[34];
        const int ig = y0 + i;
        const int jg = x0 + j;
        if (ig < OUT_HW && jg < OUT_HW) {
            const size_t oidx = (((size_t)b * (NDISP * NDISP) + (size_t)dyi * NDISP + d)
                                 * OUT_HW + ig) * OUT_HW + jg;
            out[oidx] = s * scale;
        }
    }
}

extern "C" void kernel_launch(void* const* d_in, const int* in_sizes, int n_in,
                              void* d_out, int out_size, void* d_ws, size_t ws_size,
                              hipStream_t stream) {
    const float* in1 = (const float*)d_in[0];
    const float* in2 = (const float*)d_in[1];
    float* out = (float*)d_out;

    dim3 grid(12, 12, 4 * NDISP);   // 12x12 tiles of 14 cover 156; z = b*21 + dyi
    corr_kernel<<<grid, dim3(NT), 0, stream>>>(in1, in2, out);
}

// Round 2
// 652.007 us; speedup vs baseline: 3.2702x; 3.2702x over previous
//
#include <hip/hip_runtime.h>
#include <hip/hip_bf16.h>

// Correlation (FlowNetC/PWC) cost volume via bf16 MFMA banded-GEMM.
// B=4 C=128 H=W=192, disp grid 21x21 (stride 2), K=3 window, PAD=3.
// corr[b,dyi,t,y,x] = sum_c in1[c,y+17,x+17] * in2[c,y+17+dy,x+17+2t-20]
// out[b,dyi*21+t,i,j] = (1/1152) * sum_{3x3} corr[...]
//
// Pipeline: (0) convert inputs fp32->bf16 into ws, (1) MFMA corr -> bf16 corr
// planes in ws, (2) 3x3 window sum -> fp32 out. Falls back to the round-1
// fp32 kernel if ws_size is too small.

#define C_    128
#define H_    192
#define W_    192
#define HW_   36864
#define NE_   18874368            // elems per input (4*128*192*192)
#define CORR_E 44036496           // 4*441*158*158
#define WS_NEED 163570464ull      // 2*NE_*2 + CORR_E*2 bytes

typedef __attribute__((ext_vector_type(8))) short short8;
typedef __attribute__((ext_vector_type(4))) float floatx4;

__device__ __forceinline__ float bf2f(ushort h) {
    uint u = ((uint)h) << 16;
    return __builtin_bit_cast(float, u);
}
__device__ __forceinline__ ushort f2bf(float f) {
    __hip_bfloat16 hb = __float2bfloat16(f);
    return *(ushort*)&hb;
}

// ---------------- kernel 0: fp32 -> bf16 convert ----------------
__global__ __launch_bounds__(256)
void cvt_kernel(const float* __restrict__ a, const float* __restrict__ b,
                ushort* __restrict__ dst0) {
    const float* src = blockIdx.y ? b : a;
    ushort* dst = dst0 + (size_t)blockIdx.y * NE_;
    size_t i = ((size_t)blockIdx.x * 256 + threadIdx.x) * 8;
    const float4* s4 = (const float4*)(src + i);
    float4 v0 = s4[0], v1 = s4[1];
    float f[8] = {v0.x, v0.y, v0.z, v0.w, v1.x, v1.y, v1.z, v1.w};
    uint w[4];
#pragma unroll
    for (int k = 0; k < 4; ++k)
        w[k] = (uint)f2bf(f[2 * k]) | ((uint)f2bf(f[2 * k + 1]) << 16);
    uint4 o; o.x = w[0]; o.y = w[1]; o.z = w[2]; o.w = w[3];
    *(uint4*)(dst + i) = o;
}

// ---------------- kernel 1: MFMA corr ----------------
// Block: (xtile j0=32*bx, ytile: 2 same-parity corr rows, z = b*2+q parity)
// 256 threads = 4 waves; wave = (yrow, p) with p = x-parity.
// LDS (ushort elems): B ring [2 slot][2 p][36 s][136 c] @0 (19584, frag reads
// may overrun into the gap below 21248 - results masked), corr tile @21248
// (21*68=1428, elem = t*68 + yrow*34 + x), A @22720 [2 yr][2 p][16 m][136 c].
#define CSTR 136
#define B_OFF 0
#define CORR_OFF 21248
#define A_OFF 22720
#define LDS_SH 31424   // ushorts = 62848 B

__global__ __launch_bounds__(256, 2)
void corr_mfma(const ushort* __restrict__ in1b, const ushort* __restrict__ in2b,
               ushort* __restrict__ corrw) {
    __shared__ ushort lds[LDS_SH];
    const int tid = threadIdx.x;
    const int j0 = blockIdx.x * 32;
    const int ytile = blockIdx.y;
    const int zz = blockIdx.z;
    const int b = zz >> 1, q = zz & 1;
    const int ybase = q + 4 * ytile;   // corr row of yrow 0

    // ---- stage A: A[yr][p][m][c] = in1[c, ybase+2yr+17, j0+17+2m+p] ----
    {
        const int yr = tid >> 7;
        const int c = tid & 127;
        const int row = ybase + 2 * yr + 17;   // always < 192
        const ushort* src = in1b + (size_t)b * C_ * HW_ + (size_t)c * HW_ + (size_t)row * W_;
#pragma unroll
        for (int g = 0; g < 5; ++g) {
            const int col0 = j0 + 16 + 8 * g;
            uint4 v = *(const uint4*)(src + col0);
            const uint wv[4] = {v.x, v.y, v.z, v.w};
#pragma unroll
            for (int e = 0; e < 8; ++e) {
                const int mp = col0 + e - j0 - 17;  // = 2m+p, valid 0..31
                if (mp >= 0 && mp < 32) {
                    const int p = mp & 1, m = mp >> 1;
                    const ushort h = (ushort)(wv[e >> 1] >> ((e & 1) * 16));
                    lds[A_OFF + ((((yr << 1) | p) << 4) + m) * CSTR + c] = h;
                }
            }
        }
    }

    // ---- B row staging: row r_idx -> slot r_idx&1 ----
    const int cB = tid & 127;
    const int gpar = tid >> 7;
    const ushort* in2base = in2b + (size_t)b * C_ * HW_ + (size_t)cB * HW_;
    auto stageB = [&](int r_idx) {
        const int slot = r_idx & 1;
        const int yb = ybase - 3 + 2 * r_idx;       // in2 row (may be OOB -> 0)
        const bool rowok = (yb >= 0) && (yb < H_);
        ushort* dst = lds + B_OFF + slot * (2 * 36 * CSTR);
        const ushort* srow = in2base + (ptrdiff_t)yb * W_;
#pragma unroll
        for (int k = 0; k < 5; ++k) {
            const int g = gpar + 2 * k;             // 0..9
            const int col0 = j0 - 8 + 8 * g;
            uint4 v = {0u, 0u, 0u, 0u};
            if (rowok) v = *(const uint4*)(srow + col0);
            const uint wv[4] = {v.x, v.y, v.z, v.w};
#pragma unroll
            for (int e = 0; e < 8; ++e) {
                const int col = col0 + e;
                const int ee = col - j0 + 3;        // = 2s+p, valid 0..71
                if (ee >= 0 && ee < 72) {
                    ushort h = (ushort)(wv[e >> 1] >> ((e & 1) * 16));
                    if (col < 0 || col >= W_) h = 0;
                    dst[((ee & 1) * 36 + (ee >> 1)) * CSTR + cB] = h;
                }
            }
        }
    };
    stageB(0);
    stageB(1);
    __syncthreads();

    // ---- hoisted A fragments ----
    const int wav = tid >> 6;
    const int yrow = wav >> 1, p = wav & 1;
    const int lane = tid & 63;
    const int mn = lane & 15, quad = lane >> 4;
    short8 afr[4];
    const ushort* abase = lds + A_OFF + ((((yrow << 1) | p) << 4) + mn) * CSTR + quad * 8;
#pragma unroll
    for (int kb = 0; kb < 4; ++kb)
        afr[kb] = *(const short8*)(abase + kb * 32);

    const size_t planebase = (size_t)b * 441;
    for (int dyi = 0; dyi < 21; ++dyi) {
        __syncthreads();   // staged B rows + corr tile free
        const int slot = (dyi + yrow) & 1;
        const ushort* bbase = lds + B_OFF + ((slot * 2 + p) * 36) * CSTR + quad * 8;
        floatx4 acc[3];
#pragma unroll
        for (int u3 = 0; u3 < 3; ++u3) acc[u3] = (floatx4){0.f, 0.f, 0.f, 0.f};
#pragma unroll
        for (int u3 = 0; u3 < 3; ++u3) {
            const ushort* bcol = bbase + (u3 * 16 + mn) * CSTR;
#pragma unroll
            for (int kb = 0; kb < 4; ++kb) {
                short8 bfr = *(const short8*)(bcol + kb * 32);
                acc[u3] = __builtin_amdgcn_mfma_f32_16x16x32_bf16(afr[kb], bfr, acc[u3], 0, 0, 0);
            }
        }
        // scatter C frags into corr tile: (m,n) -> t = s-m, x = 2m+p
#pragma unroll
        for (int u3 = 0; u3 < 3; ++u3) {
#pragma unroll
            for (int v = 0; v < 4; ++v) {
                const int mr = quad * 4 + v;
                const int t = u3 * 16 + mn - mr;
                if (t >= 0 && t <= 20)
                    lds[CORR_OFF + t * 68 + yrow * 34 + 2 * mr + p] = f2bf(acc[u3][v]);
            }
        }
        __syncthreads();   // corr tile complete, frag reads done
        // coalesced store of corr tile (dword = 2 bf16)
#pragma unroll
        for (int it = 0; it < 3; ++it) {
            const int idx = tid + it * 256;
            if (idx < 672) {
                const int t = idx >> 5, rem = idx & 31;
                const int yy = rem >> 4, x2 = (rem & 15) << 1;
                const uint val = *(const uint*)(lds + CORR_OFF + t * 68 + yy * 34 + x2);
                const int Y = ybase + 2 * yy, X = j0 + x2;
                if (Y < 158 && X < 158) {
                    const size_t off = ((planebase + (size_t)(dyi * 21 + t)) * 158 + Y) * 158 + X;
                    *(uint*)(corrw + off) = val;
                }
            }
        }
        if (dyi < 20) stageB(dyi + 2);   // safe: frag reads of this dyi done
    }
}

// ---------------- kernel 2: 3x3 window sum ----------------
__global__ __launch_bounds__(192)
void window_kernel(const ushort* __restrict__ corrw, float* __restrict__ out) {
    __shared__ uint wsl[800];   // 10 rows x 80 dwords (160 bf16 cols)
    const int tid = threadIdx.x;
    const int i0 = blockIdx.x * 8;
    const int plane = blockIdx.y;
    const ushort* cp = corrw + (size_t)plane * 24964;
    for (int task = tid; task < 800; task += 192) {
        const int r = task / 80;
        const int dc = task - r * 80;
        const int row = i0 + r;
        if (dc < 79 && row < 158)
            wsl[task] = *(const uint*)(cp + row * 158 + dc * 2);
    }
    __syncthreads();
    if (tid < 156) {
        const ushort* cl = (const ushort*)wsl;
        float S[10];
#pragma unroll
        for (int r = 0; r < 10; ++r) {
            const ushort* rp = cl + r * 160 + tid;
            S[r] = bf2f(rp[0]) + bf2f(rp[1]) + bf2f(rp[2]);
        }
        const float sc = 1.f / 1152.f;
#pragma unroll
        for (int r = 0; r < 8; ++r) {
            const int row = i0 + r;
            if (row < 156)
                out[(size_t)plane * 24336 + (size_t)row * 156 + tid] =
                    (S[r] + S[r + 1] + S[r + 2]) * sc;
        }
    }
}

// ---------------- fallback (round-1 fp32 kernel) ----------------
#define OUT_HW 156
#define NDISP 21
#define TILE_OUT 14
#define TILE_CORR 16
#define S2W 56
#define NT 256

__global__ __launch_bounds__(NT, 4)
void corr_fallback(const float* __restrict__ in1, const float* __restrict__ in2,
                   float* __restrict__ out) {
    __shared__ float s2s[TILE_CORR * S2W];
    __shared__ float corrs[NDISP * TILE_CORR * TILE_CORR];
    const int tid = threadIdx.x;
    const int tx = tid & 15;
    const int ty = tid >> 4;
    const int tj = blockIdx.x;
    const int ti = blockIdx.y;
    const int z = blockIdx.z;
    const int b = z / NDISP;
    const int dyi = z - b * NDISP;
    const int dy = 2 * dyi - 20;
    const int y0 = ti * TILE_OUT;
    const int x0 = tj * TILE_OUT;
    const int y = y0 + ty;
    const int x = x0 + tx;
    float acc[NDISP];
#pragma unroll
    for (int d = 0; d < NDISP; ++d) acc[d] = 0.f;
    const float* p1 = in1 + (size_t)b * C_ * HW_ + (size_t)(y + 17) * W_ + (x + 17);
    const float* p2base = in2 + (size_t)b * C_ * HW_;
    for (int c = 0; c < C_; ++c) {
        const float a = p1[(size_t)c * HW_];
        const float* p2 = p2base + (size_t)c * HW_;
        for (int idx = tid; idx < TILE_CORR * S2W; idx += NT) {
            const int r = idx / S2W;
            const int cc = idx - r * S2W;
            const int gr = y0 + r + 17 + dy;
            const int gc = x0 + cc - 3;
            float v = 0.f;
            if ((unsigned)gr < H_ && (unsigned)gc < W_) v = p2[gr * W_ + gc];
            s2s[idx] = v;
        }
        __syncthreads();
        const float* srow = &s2s[ty * S2W + tx];
#pragma unroll
        for (int d = 0; d < NDISP; ++d) acc[d] += a * srow[2 * d];
        __syncthreads();
    }
#pragma unroll
    for (int d = 0; d < NDISP; ++d)
        corrs[d * (TILE_CORR * TILE_CORR) + tid] = acc[d];
    __syncthreads();
    const float scale = 1.f / 1152.f;
    for (int o = tid; o < NDISP * TILE_OUT * TILE_OUT; o += NT) {
        const int d = o / (TILE_OUT * TILE_OUT);
        const int rem = o - d * (TILE_OUT * TILE_OUT);
        const int i = rem / TILE_OUT;
        const int j = rem - i * TILE_OUT;
        const float* cpt = &corrs[d * (TILE_CORR * TILE_CORR) + i * TILE_CORR + j];
        const float s = cpt[0] + cpt[1] + cpt[2]
                      + cpt[16] + cpt[17] + cpt[18]
                      + cpt[32] + cpt[33] + cpt[34];
        const int ig = y0 + i;
        const int jg = x0 + j;
        if (ig < OUT_HW && jg < OUT_HW) {
            const size_t oidx = (((size_t)b * (NDISP * NDISP) + (size_t)dyi * NDISP + d)
                                 * OUT_HW + ig) * OUT_HW + jg;
            out[oidx] = s * scale;
        }
    }
}

extern "C" void kernel_launch(void* const* d_in, const int* in_sizes, int n_in,
                              void* d_out, int out_size, void* d_ws, size_t ws_size,
                              hipStream_t stream) {
    const float* in1 = (const float*)d_in[0];
    const float* in2 = (const float*)d_in[1];
    float* out = (float*)d_out;

    if (ws_size >= WS_NEED) {
        ushort* wsp = (ushort*)d_ws;
        ushort* in1b = wsp;
        ushort* in2b = wsp + (size_t)NE_;
        ushort* corrw = wsp + (size_t)2 * NE_;
        cvt_kernel<<<dim3(9216, 2), 256, 0, stream>>>(in1, in2, wsp);
        corr_mfma<<<dim3(5, 40, 8), 256, 0, stream>>>(in1b, in2b, corrw);
        window_kernel<<<dim3(20, 1764), 192, 0, stream>>>(corrw, out);
    } else {
        corr_fallback<<<dim3(12, 12, 84), 256, 0, stream>>>(in1, in2, out);
    }
}